// Round 8
// baseline (18208.330 us; speedup 1.0000x reference)
//
#include <hip/hip_runtime.h>
#include <cstdint>

typedef unsigned long long ull;

#define B_ 4
#define N_ 16384
#define C_ 64
#define O_ 128
#define S_ 4096
#define K_ 32
#define CK_ 67  // C+3

// ---------------------------------------------------------------------------
// Counting sort by 16^3 Morton cell (UNCHANGED -- verified rounds 4-7).
// ---------------------------------------------------------------------------
__device__ __forceinline__ unsigned part3_4(unsigned v) {
  return (v & 1u) | ((v & 2u) << 2) | ((v & 4u) << 4) | ((v & 8u) << 6);
}

__launch_bounds__(1024, 1)
__global__ void sort_kernel(const float* __restrict__ xyz,
                            float4* __restrict__ sorted) {
  const int b = blockIdx.x, t = threadIdx.x;
  const int lane = t & 63, wid = t >> 6;
  __shared__ unsigned hist[4096];
  __shared__ unsigned wsum[16];
  for (int i = t; i < 4096; i += 1024) hist[i] = 0u;
  __syncthreads();
  const float* base = xyz + (size_t)b * N_ * 3;
  int cell[16];
#pragma unroll
  for (int j = 0; j < 16; ++j) {
    int p = j * 1024 + t;
    float x = base[p * 3 + 0], y = base[p * 3 + 1], z = base[p * 3 + 2];
    int cx = (int)floorf((x + 6.0f) * (16.0f / 12.0f));
    int cy = (int)floorf((y + 6.0f) * (16.0f / 12.0f));
    int cz = (int)floorf((z + 6.0f) * (16.0f / 12.0f));
    cx = min(max(cx, 0), 15); cy = min(max(cy, 0), 15); cz = min(max(cz, 0), 15);
    int m = (int)(part3_4((unsigned)cx) | (part3_4((unsigned)cy) << 1) |
                  (part3_4((unsigned)cz) << 2));
    cell[j] = m;
    atomicAdd(&hist[m], 1u);
  }
  __syncthreads();
  unsigned h0 = hist[4 * t + 0], h1 = hist[4 * t + 1];
  unsigned h2 = hist[4 * t + 2], h3 = hist[4 * t + 3];
  unsigned s4 = h0 + h1 + h2 + h3;
  unsigned inc = s4;
#pragma unroll
  for (int off = 1; off < 64; off <<= 1) {
    unsigned n = __shfl_up(inc, off);
    if (lane >= off) inc += n;
  }
  if (lane == 63) wsum[wid] = inc;
  __syncthreads();
  if (t < 16) {
    unsigned v = wsum[t], iv = v;
#pragma unroll
    for (int off = 1; off < 16; off <<= 1) {
      unsigned n = __shfl_up(iv, off);
      if (t >= off) iv += n;
    }
    wsum[t] = iv - v;
  }
  __syncthreads();
  unsigned st = wsum[wid] + (inc - s4);
  hist[4 * t + 0] = st;
  hist[4 * t + 1] = st + h0;
  hist[4 * t + 2] = st + h0 + h1;
  hist[4 * t + 3] = st + h0 + h1 + h2;
  __syncthreads();
#pragma unroll
  for (int j = 0; j < 16; ++j) {
    int p = j * 1024 + t;
    float x = base[p * 3 + 0], y = base[p * 3 + 1], z = base[p * 3 + 2];
    unsigned pos = atomicAdd(&hist[cell[j]], 1u);
    float4 o;
    o.x = x; o.y = y; o.z = z; o.w = __uint_as_float((unsigned)p);
    sorted[(size_t)b * N_ + pos] = o;
  }
}

// ---------------------------------------------------------------------------
// FPS v7: lazy skip (validated r4-r7) + PIPELINED update loads.
// Update loop = explicit 2-deep double buffer (vA/vB, 8 float4 each): 8 loads
// in flight per wait -> ~4x250cyc latency instead of 32 serialized L2 hits
// (r7's 8300 cyc/iter). Sequential bv/bo compare (low reg pressure; the r7
// kj[32] tree blew the budget and defeated batching).
// Exactness unchanged: skip test lb*(1-2e-5) >= bucketMax; distance expr
// byte-identical to verified rounds; key = dist|~og|pos == jnp.argmax order.
// ---------------------------------------------------------------------------
#define FPS_PROC(cur, cbase)                                              \
  _Pragma("unroll")                                                       \
  for (int j = 0; j < 8; ++j) {                                           \
    float dx = cur[j].x - fx;                                             \
    float dy = cur[j].y - fy;                                             \
    float dz = cur[j].z - fz;                                             \
    float d = dx * dx + dy * dy + dz * dz;                                \
    float m = fminf(dist[(cbase) + j], d);                                \
    dist[(cbase) + j] = m;                                                \
    unsigned og = __float_as_uint(cur[j].w);                              \
    bool better = (m > bv) || ((m == bv) && (og < bo));                   \
    if (better) { bv = m; bo = og; bp = (cbase) + j; }                    \
  }

__launch_bounds__(512, 1)
__global__ void fps_kernel(const float* __restrict__ xyz,
                           const float4* __restrict__ sorted,
                           float* __restrict__ new_xyz) {
#pragma clang fp contract(off)
  const int b = blockIdx.x, t = threadIdx.x;
  const int lane = t & 63, wid = t >> 6;  // 8 waves
  const float4* sb = sorted + (size_t)b * N_;
  float dist[32];
  float lox, hix, loy, hiy, loz, hiz;
  {
    float4 v0 = sb[32 * t];
    lox = hix = v0.x; loy = hiy = v0.y; loz = hiz = v0.z;
#pragma unroll
    for (int j = 1; j < 32; ++j) {
      float4 v = sb[32 * t + j];
      lox = fminf(lox, v.x); hix = fmaxf(hix, v.x);
      loy = fminf(loy, v.y); hiy = fmaxf(hiy, v.y);
      loz = fminf(loz, v.z); hiz = fmaxf(hiz, v.z);
    }
  }
#pragma unroll
  for (int j = 0; j < 32; ++j) dist[j] = 1e10f;
  __shared__ ull s_key[2][8];
  const float* ob = xyz + (size_t)b * N_ * 3;
  float fx = ob[0], fy = ob[1], fz = ob[2];  // far = 0 initially
  ull mykey = ((ull)__float_as_uint(1e10f)) << 28;  // bmax=1e10 -> all update s=0
  ull wkey = 0;  // wave-uniform best; set at s=0 (all waves update then)
  for (int s = 0; s < S_; ++s) {
    const int buf = s & 1;
    if (t == 0) {
      float* o = new_xyz + ((size_t)b * S_ + s) * 3;
      o[0] = fx; o[1] = fy; o[2] = fz;
    }
    float dxm = fmaxf(fmaxf(lox - fx, fx - hix), 0.0f);
    float dym = fmaxf(fmaxf(loy - fy, fy - hiy), 0.0f);
    float dzm = fmaxf(fmaxf(loz - fz, fz - hiz), 0.0f);
    float lb = dxm * dxm + dym * dym + dzm * dzm;
    float bmax = __uint_as_float((unsigned)(mykey >> 28));
    bool upd = (lb * 0.99998f < bmax);  // conservative (covers f32 rounding)
    if (__any(upd)) {
      if (upd) {
        float bv = -1.0f;
        unsigned bo = 0xFFFFFFFFu;
        int bp = 0;
        float4 vA[8], vB[8];
#pragma unroll
        for (int j = 0; j < 8; ++j) vA[j] = sb[32 * t + j];       // chunk 0
#pragma unroll
        for (int j = 0; j < 8; ++j) vB[j] = sb[32 * t + 8 + j];   // chunk 1
        FPS_PROC(vA, 0)
#pragma unroll
        for (int j = 0; j < 8; ++j) vA[j] = sb[32 * t + 16 + j];  // chunk 2
        FPS_PROC(vB, 8)
#pragma unroll
        for (int j = 0; j < 8; ++j) vB[j] = sb[32 * t + 24 + j];  // chunk 3
        FPS_PROC(vA, 16)
        FPS_PROC(vB, 24)
        mykey = (((ull)__float_as_uint(bv)) << 28) |
                (((ull)((~bo) & 0x3FFFu)) << 14) | (unsigned)(32 * t + bp);
      }
      ull k = mykey;
#pragma unroll
      for (int off = 1; off < 64; off <<= 1) {
        ull o = __shfl_xor(k, off);
        if (o > k) k = o;
      }
      wkey = k;
    }
    if (lane == 0) s_key[buf][wid] = wkey;
    __syncthreads();
    ull kb = s_key[buf][0];
#pragma unroll
    for (int w = 1; w < 8; ++w) {
      ull o = s_key[buf][w];
      if (o > kb) kb = o;
    }
    float4 c = sb[(unsigned)(kb & 0x3FFFu)];  // uniform addr, L1/L2-hot
    fx = c.x; fy = c.y; fz = c.z;
  }
}

// ---------------------------------------------------------------------------
// KNN over new_xyz (UNCHANGED -- verified).
// ---------------------------------------------------------------------------
__launch_bounds__(256, 2)
__global__ void knn_kernel(const float* __restrict__ new_xyz,
                           int* __restrict__ knn_idx) {
  const int b = blockIdx.y;
  const int t = threadIdx.x;
  const int q = blockIdx.x * 256 + t;
  __shared__ float sx[S_], sy[S_], sz[S_], sn[S_];
  const float* nb = new_xyz + (size_t)b * S_ * 3;
  for (int i = t; i < S_; i += 256) {
    float x = nb[i * 3 + 0], y = nb[i * 3 + 1], z = nb[i * 3 + 2];
    sx[i] = x; sy[i] = y; sz[i] = z;
    sn[i] = fmaf(z, z, fmaf(y, y, x * x));
  }
  __syncthreads();
  const float qx = sx[q], qy = sy[q], qz = sz[q], qn = sn[q];
  unsigned long long kv[K_];
#pragma unroll
  for (int j = 0; j < K_; ++j) kv[j] = 0ull;
  for (int i = 0; i < S_; ++i) {
    float inner = fmaf(sz[i], qz, fmaf(sy[i], qy, sx[i] * qx));
    float score = (2.0f * inner - qn) - sn[i];
    unsigned u = __float_as_uint(score);
    u ^= (unsigned)((int)u >> 31) | 0x80000000u;
    unsigned long long nk = ((unsigned long long)u << 32) | (unsigned)(~i);
    if (nk > kv[K_ - 1]) {
#pragma unroll
      for (int j = K_ - 1; j >= 1; --j) {
        bool upPrev = nk > kv[j - 1];
        kv[j] = upPrev ? kv[j - 1] : ((nk > kv[j]) ? nk : kv[j]);
      }
      if (nk > kv[0]) kv[0] = nk;
    }
  }
#pragma unroll
  for (int j = 0; j < K_; ++j)
    knn_idx[((size_t)b * S_ + q) * K_ + j] = (int)(~(unsigned)kv[j]);
}

// ---------------------------------------------------------------------------
// MLP v2 (UNCHANGED -- verified, no spills).
// ---------------------------------------------------------------------------
#define W1S 76
#define W2S 132
#define CLS 72
#define HPS 132

__launch_bounds__(256, 1)
__global__ void mlp_kernel(const float* __restrict__ xyz,
                           const float* __restrict__ features,
                           const float* __restrict__ new_xyz,
                           const int* __restrict__ knn_idx,
                           const float* __restrict__ W1,
                           const float* __restrict__ b1,
                           const float* __restrict__ gamma,
                           const float* __restrict__ beta,
                           const float* __restrict__ W2,
                           const float* __restrict__ b2,
                           float* __restrict__ out_feat) {
  __shared__ float w1T[O_][W1S];
  __shared__ float w2T[O_][W2S];
  __shared__ float c_l[K_][CLS];
  __shared__ float hp[K_][HPS];
  __shared__ float pmaxl[8][O_];

  const int t = threadIdx.x;
  const int g = t >> 5;
  const int cg = t & 31;

  for (int e = t; e < CK_ * O_; e += 256) {
    int k = e >> 7, c = e & (O_ - 1);
    w1T[c][k] = W1[e];
  }
  if (t < O_) {
#pragma unroll
    for (int k = CK_; k < 68; ++k) w1T[t][k] = 0.0f;
  }
  for (int e = t; e < O_ * O_; e += 256) {
    int k = e >> 7, c = e & (O_ - 1);
    w2T[c][k] = W2[e];
  }
  float bb1[4], gm[4], bt[4], bb2 = 0.0f;
#pragma unroll
  for (int j = 0; j < 4; ++j) {
    bb1[j] = b1[cg + 32 * j];
    gm[j] = gamma[cg + 32 * j];
    bt[j] = beta[cg + 32 * j];
  }
  if (t < O_) bb2 = b2[t];

  const int bs0 = blockIdx.x * 64;
  const int b = bs0 >> 12;
  const float* fb = features + (size_t)b * N_ * C_;
  const float* xb = xyz + (size_t)b * N_ * 3;

  __syncthreads();

  for (int is = 0; is < 64; ++is) {
    const int bs = bs0 + is;
    const float qx = new_xyz[(size_t)bs * 3 + 0];
    const float qy = new_xyz[(size_t)bs * 3 + 1];
    const float qz = new_xyz[(size_t)bs * 3 + 2];

    for (int e = t; e < K_ * 68; e += 256) {
      int r = e / 68;
      int k = e - r * 68;
      int nbi = knn_idx[(size_t)bs * K_ + r];
      float v;
      if (k < C_) {
        v = fb[(size_t)nbi * C_ + k];
      } else if (k < CK_) {
        float coord = xb[nbi * 3 + (k - C_)];
        float qq = (k == C_) ? qx : ((k == C_ + 1) ? qy : qz);
        v = coord - qq;
      } else {
        v = 0.0f;
      }
      c_l[r][k] = v;
    }
    __syncthreads();

    float h[4][4];
#pragma unroll
    for (int i = 0; i < 4; ++i)
#pragma unroll
      for (int j = 0; j < 4; ++j) h[i][j] = 0.0f;
#pragma unroll
    for (int kc = 0; kc < 17; ++kc) {
      float4 w[4], a[4];
#pragma unroll
      for (int j = 0; j < 4; ++j)
        w[j] = *reinterpret_cast<const float4*>(&w1T[cg + 32 * j][kc * 4]);
#pragma unroll
      for (int i = 0; i < 4; ++i)
        a[i] = *reinterpret_cast<const float4*>(&c_l[4 * g + i][kc * 4]);
#pragma unroll
      for (int i = 0; i < 4; ++i)
#pragma unroll
        for (int j = 0; j < 4; ++j) {
          h[i][j] = fmaf(a[i].x, w[j].x, h[i][j]);
          h[i][j] = fmaf(a[i].y, w[j].y, h[i][j]);
          h[i][j] = fmaf(a[i].z, w[j].z, h[i][j]);
          h[i][j] = fmaf(a[i].w, w[j].w, h[i][j]);
        }
    }
#pragma unroll
    for (int i = 0; i < 4; ++i)
#pragma unroll
      for (int j = 0; j < 4; ++j) h[i][j] += bb1[j];

#pragma unroll
    for (int i = 0; i < 4; ++i) {
      float s1 = (h[i][0] + h[i][1]) + (h[i][2] + h[i][3]);
      float s2 = ((h[i][0] * h[i][0] + h[i][1] * h[i][1]) +
                  (h[i][2] * h[i][2] + h[i][3] * h[i][3]));
#pragma unroll
      for (int off = 1; off <= 16; off <<= 1) {
        s1 += __shfl_xor(s1, off);
        s2 += __shfl_xor(s2, off);
      }
      float mu = s1 * (1.0f / 128.0f);
      float va = fmaf(mu, -mu, s2 * (1.0f / 128.0f));
      float rs = rsqrtf(va + 1e-5f);
#pragma unroll
      for (int j = 0; j < 4; ++j) {
        float hv = fmaf((h[i][j] - mu) * rs, gm[j], bt[j]);
        hp[4 * g + i][cg + 32 * j] = fmaxf(hv, 0.0f);
      }
    }
    __syncthreads();

    float acc[4][4];
#pragma unroll
    for (int i = 0; i < 4; ++i)
#pragma unroll
      for (int j = 0; j < 4; ++j) acc[i][j] = 0.0f;
#pragma unroll 8
    for (int kc = 0; kc < 32; ++kc) {
      float4 w[4], a[4];
#pragma unroll
      for (int j = 0; j < 4; ++j)
        w[j] = *reinterpret_cast<const float4*>(&w2T[cg + 32 * j][kc * 4]);
#pragma unroll
      for (int i = 0; i < 4; ++i)
        a[i] = *reinterpret_cast<const float4*>(&hp[4 * g + i][kc * 4]);
#pragma unroll
      for (int i = 0; i < 4; ++i)
#pragma unroll
        for (int j = 0; j < 4; ++j) {
          acc[i][j] = fmaf(a[i].x, w[j].x, acc[i][j]);
          acc[i][j] = fmaf(a[i].y, w[j].y, acc[i][j]);
          acc[i][j] = fmaf(a[i].z, w[j].z, acc[i][j]);
          acc[i][j] = fmaf(a[i].w, w[j].w, acc[i][j]);
        }
    }
#pragma unroll
    for (int j = 0; j < 4; ++j) {
      float pm = fmaxf(fmaxf(acc[0][j], acc[1][j]), fmaxf(acc[2][j], acc[3][j]));
      pmaxl[g][cg + 32 * j] = pm;
    }
    __syncthreads();

    if (t < O_) {
      float m = pmaxl[0][t];
#pragma unroll
      for (int w = 1; w < 8; ++w) m = fmaxf(m, pmaxl[w][t]);
      out_feat[(size_t)bs * O_ + t] = m + bb2;
    }
    __syncthreads();
  }
}

extern "C" void kernel_launch(void* const* d_in, const int* in_sizes, int n_in,
                              void* d_out, int out_size, void* d_ws, size_t ws_size,
                              hipStream_t stream) {
  const float* xyz      = (const float*)d_in[0];
  const float* features = (const float*)d_in[1];
  const float* W1       = (const float*)d_in[2];
  const float* b1       = (const float*)d_in[3];
  const float* gamma    = (const float*)d_in[4];
  const float* beta     = (const float*)d_in[5];
  const float* W2       = (const float*)d_in[6];
  const float* b2       = (const float*)d_in[7];

  float* out      = (float*)d_out;
  float* new_xyz  = out;                          // [4,4096,3]
  float* new_feat = out + (size_t)B_ * S_ * 3;    // [4,4096,128]
  int* knn_idx = (int*)d_ws;                      // [4,4096,32] = 2 MB
  float4* sorted = (float4*)((char*)d_ws + (size_t)B_ * S_ * K_ * 4);  // 1 MB

  sort_kernel<<<B_, 1024, 0, stream>>>(xyz, sorted);
  fps_kernel<<<B_, 512, 0, stream>>>(xyz, sorted, new_xyz);
  knn_kernel<<<dim3(S_ / 256, B_), 256, 0, stream>>>(new_xyz, knn_idx);
  mlp_kernel<<<B_ * S_ / 64, 256, 0, stream>>>(xyz, features, new_xyz, knn_idx,
                                               W1, b1, gamma, beta, W2, b2,
                                               new_feat);
}

// Round 9
// 11000.198 us; speedup vs baseline: 1.6553x; 1.6553x over previous
//
#include <hip/hip_runtime.h>
#include <cstdint>

typedef unsigned long long ull;

#define B_ 4
#define N_ 16384
#define C_ 64
#define O_ 128
#define S_ 4096
#define K_ 32
#define CK_ 67  // C+3

// ---------------------------------------------------------------------------
// Counting sort by 16^3 Morton cell (UNCHANGED -- verified rounds 4-8).
// ---------------------------------------------------------------------------
__device__ __forceinline__ unsigned part3_4(unsigned v) {
  return (v & 1u) | ((v & 2u) << 2) | ((v & 4u) << 4) | ((v & 8u) << 6);
}

__launch_bounds__(1024, 1)
__global__ void sort_kernel(const float* __restrict__ xyz,
                            float4* __restrict__ sorted) {
  const int b = blockIdx.x, t = threadIdx.x;
  const int lane = t & 63, wid = t >> 6;
  __shared__ unsigned hist[4096];
  __shared__ unsigned wsum[16];
  for (int i = t; i < 4096; i += 1024) hist[i] = 0u;
  __syncthreads();
  const float* base = xyz + (size_t)b * N_ * 3;
  int cell[16];
#pragma unroll
  for (int j = 0; j < 16; ++j) {
    int p = j * 1024 + t;
    float x = base[p * 3 + 0], y = base[p * 3 + 1], z = base[p * 3 + 2];
    int cx = (int)floorf((x + 6.0f) * (16.0f / 12.0f));
    int cy = (int)floorf((y + 6.0f) * (16.0f / 12.0f));
    int cz = (int)floorf((z + 6.0f) * (16.0f / 12.0f));
    cx = min(max(cx, 0), 15); cy = min(max(cy, 0), 15); cz = min(max(cz, 0), 15);
    int m = (int)(part3_4((unsigned)cx) | (part3_4((unsigned)cy) << 1) |
                  (part3_4((unsigned)cz) << 2));
    cell[j] = m;
    atomicAdd(&hist[m], 1u);
  }
  __syncthreads();
  unsigned h0 = hist[4 * t + 0], h1 = hist[4 * t + 1];
  unsigned h2 = hist[4 * t + 2], h3 = hist[4 * t + 3];
  unsigned s4 = h0 + h1 + h2 + h3;
  unsigned inc = s4;
#pragma unroll
  for (int off = 1; off < 64; off <<= 1) {
    unsigned n = __shfl_up(inc, off);
    if (lane >= off) inc += n;
  }
  if (lane == 63) wsum[wid] = inc;
  __syncthreads();
  if (t < 16) {
    unsigned v = wsum[t], iv = v;
#pragma unroll
    for (int off = 1; off < 16; off <<= 1) {
      unsigned n = __shfl_up(iv, off);
      if (t >= off) iv += n;
    }
    wsum[t] = iv - v;
  }
  __syncthreads();
  unsigned st = wsum[wid] + (inc - s4);
  hist[4 * t + 0] = st;
  hist[4 * t + 1] = st + h0;
  hist[4 * t + 2] = st + h0 + h1;
  hist[4 * t + 3] = st + h0 + h1 + h2;
  __syncthreads();
#pragma unroll
  for (int j = 0; j < 16; ++j) {
    int p = j * 1024 + t;
    float x = base[p * 3 + 0], y = base[p * 3 + 1], z = base[p * 3 + 2];
    unsigned pos = atomicAdd(&hist[cell[j]], 1u);
    float4 o;
    o.x = x; o.y = y; o.z = z; o.w = __uint_as_float((unsigned)p);
    sorted[(size_t)b * N_ + pos] = o;
  }
}

// ---------------------------------------------------------------------------
// FPS v8 (cooperative-lazy): dist[16384] in LDS; 256 regions x 64 pts with
// LDS AABB + running max-key. Per iter: region test -> compact needed-list ->
// one WAVE per needed region (coalesced 1024B load, LDS min-update, 6-lvl
// u64 shuffle -> regmax) -> 256-slot reduce -> uniform coord fetch.
// No per-thread arrays => no register-pressure failure mode (r4-r8 lesson).
// Exactness: same contract(off) distance expr, same min-update values, same
// key order (dist desc, orig asc; pos bits never decide - og unique).
// ---------------------------------------------------------------------------
__launch_bounds__(512, 1)
__global__ void fps_kernel(const float* __restrict__ xyz,
                           const float4* __restrict__ sorted,
                           float* __restrict__ new_xyz) {
#pragma clang fp contract(off)
  const int b = blockIdx.x, t = threadIdx.x;
  const int lane = t & 63, wid = t >> 6;  // 8 waves
  const float4* sb = sorted + (size_t)b * N_;
  __shared__ float lds_dist[N_];       // 64 KB
  __shared__ float aabb[256][6];       // 6 KB
  __shared__ ull regmax[256];          // 2 KB
  __shared__ unsigned short list_[256];
  __shared__ unsigned cnt[2];
  __shared__ ull s_wbest[8];

  for (int i = t; i < N_; i += 512) lds_dist[i] = 1e10f;
  const ull INITKEY = ((ull)__float_as_uint(1e10f)) << 28;
  for (int r = t; r < 256; r += 512) regmax[r] = INITKEY;
  if (t == 0) { cnt[0] = 0u; cnt[1] = 0u; }
  for (int r = wid; r < 256; r += 8) {
    float4 v = sb[r * 64 + lane];
    float lx = v.x, hx = v.x, ly = v.y, hy = v.y, lz = v.z, hz = v.z;
#pragma unroll
    for (int off = 1; off < 64; off <<= 1) {
      lx = fminf(lx, __shfl_xor(lx, off)); hx = fmaxf(hx, __shfl_xor(hx, off));
      ly = fminf(ly, __shfl_xor(ly, off)); hy = fmaxf(hy, __shfl_xor(hy, off));
      lz = fminf(lz, __shfl_xor(lz, off)); hz = fmaxf(hz, __shfl_xor(hz, off));
    }
    if (lane == 0) {
      aabb[r][0] = lx; aabb[r][1] = hx; aabb[r][2] = ly;
      aabb[r][3] = hy; aabb[r][4] = lz; aabb[r][5] = hz;
    }
  }
  const float* ob = xyz + (size_t)b * N_ * 3;
  float fx = ob[0], fy = ob[1], fz = ob[2];  // far = 0 initially
  __syncthreads();

  for (int s = 0; s < S_; ++s) {
    const int buf = s & 1;
    if (t == 0) {
      float* o = new_xyz + ((size_t)b * S_ + s) * 3;
      o[0] = fx; o[1] = fy; o[2] = fz;
      cnt[buf ^ 1] = 0u;  // pre-zero next iteration's counter
    }
    if (t < 256) {
      float dxm = fmaxf(fmaxf(aabb[t][0] - fx, fx - aabb[t][1]), 0.0f);
      float dym = fmaxf(fmaxf(aabb[t][2] - fy, fy - aabb[t][3]), 0.0f);
      float dzm = fmaxf(fmaxf(aabb[t][4] - fz, fz - aabb[t][5]), 0.0f);
      float lb = dxm * dxm + dym * dym + dzm * dzm;
      float bmax = __uint_as_float((unsigned)(regmax[t] >> 28));
      if (lb * 0.99998f < bmax) {  // conservative skip (covers f32 rounding)
        unsigned idx = atomicAdd(&cnt[buf], 1u);
        list_[idx] = (unsigned short)t;
      }
    }
    __syncthreads();
    const int nneed = (int)cnt[buf];  // >= 1 (winner's region has lb = 0)
    for (int p = 0; p < nneed; p += 8) {
      const int li = p + wid;
      if (li < nneed) {  // wave-uniform predicate
        const int r = list_[li];
        float4 v = sb[r * 64 + lane];  // coalesced 1024B, L2-hot
        float dx = v.x - fx;
        float dy = v.y - fy;
        float dz = v.z - fz;
        float d = dx * dx + dy * dy + dz * dz;  // contract off, verified form
        const int pi = r * 64 + lane;
        float m = fminf(lds_dist[pi], d);
        lds_dist[pi] = m;
        unsigned og = __float_as_uint(v.w);
        ull key = (((ull)__float_as_uint(m)) << 28) |
                  (((ull)((~og) & 0x3FFFu)) << 14) | (unsigned)pi;
#pragma unroll
        for (int off = 1; off < 64; off <<= 1) {
          ull o = __shfl_xor(key, off);
          if (o > key) key = o;
        }
        if (lane == 0) regmax[r] = key;
      }
    }
    __syncthreads();
    ull k = 0;
    if (lane < 32) k = regmax[wid * 32 + lane];
#pragma unroll
    for (int off = 1; off < 64; off <<= 1) {
      ull o = __shfl_xor(k, off);
      if (o > k) k = o;
    }
    if (lane == 0) s_wbest[wid] = k;
    __syncthreads();
    ull kb = s_wbest[0];
#pragma unroll
    for (int w = 1; w < 8; ++w) {
      ull o = s_wbest[w];
      if (o > kb) kb = o;
    }
    float4 c = sb[(unsigned)(kb & 0x3FFFu)];  // uniform addr, cache-hot
    fx = c.x; fy = c.y; fz = c.z;
  }
}

// ---------------------------------------------------------------------------
// KNN over new_xyz (UNCHANGED -- verified).
// ---------------------------------------------------------------------------
__launch_bounds__(256, 2)
__global__ void knn_kernel(const float* __restrict__ new_xyz,
                           int* __restrict__ knn_idx) {
  const int b = blockIdx.y;
  const int t = threadIdx.x;
  const int q = blockIdx.x * 256 + t;
  __shared__ float sx[S_], sy[S_], sz[S_], sn[S_];
  const float* nb = new_xyz + (size_t)b * S_ * 3;
  for (int i = t; i < S_; i += 256) {
    float x = nb[i * 3 + 0], y = nb[i * 3 + 1], z = nb[i * 3 + 2];
    sx[i] = x; sy[i] = y; sz[i] = z;
    sn[i] = fmaf(z, z, fmaf(y, y, x * x));
  }
  __syncthreads();
  const float qx = sx[q], qy = sy[q], qz = sz[q], qn = sn[q];
  unsigned long long kv[K_];
#pragma unroll
  for (int j = 0; j < K_; ++j) kv[j] = 0ull;
  for (int i = 0; i < S_; ++i) {
    float inner = fmaf(sz[i], qz, fmaf(sy[i], qy, sx[i] * qx));
    float score = (2.0f * inner - qn) - sn[i];
    unsigned u = __float_as_uint(score);
    u ^= (unsigned)((int)u >> 31) | 0x80000000u;
    unsigned long long nk = ((unsigned long long)u << 32) | (unsigned)(~i);
    if (nk > kv[K_ - 1]) {
#pragma unroll
      for (int j = K_ - 1; j >= 1; --j) {
        bool upPrev = nk > kv[j - 1];
        kv[j] = upPrev ? kv[j - 1] : ((nk > kv[j]) ? nk : kv[j]);
      }
      if (nk > kv[0]) kv[0] = nk;
    }
  }
#pragma unroll
  for (int j = 0; j < K_; ++j)
    knn_idx[((size_t)b * S_ + q) * K_ + j] = (int)(~(unsigned)kv[j]);
}

// ---------------------------------------------------------------------------
// MLP v2 (UNCHANGED -- verified, no spills).
// ---------------------------------------------------------------------------
#define W1S 76
#define W2S 132
#define CLS 72
#define HPS 132

__launch_bounds__(256, 1)
__global__ void mlp_kernel(const float* __restrict__ xyz,
                           const float* __restrict__ features,
                           const float* __restrict__ new_xyz,
                           const int* __restrict__ knn_idx,
                           const float* __restrict__ W1,
                           const float* __restrict__ b1,
                           const float* __restrict__ gamma,
                           const float* __restrict__ beta,
                           const float* __restrict__ W2,
                           const float* __restrict__ b2,
                           float* __restrict__ out_feat) {
  __shared__ float w1T[O_][W1S];
  __shared__ float w2T[O_][W2S];
  __shared__ float c_l[K_][CLS];
  __shared__ float hp[K_][HPS];
  __shared__ float pmaxl[8][O_];

  const int t = threadIdx.x;
  const int g = t >> 5;
  const int cg = t & 31;

  for (int e = t; e < CK_ * O_; e += 256) {
    int k = e >> 7, c = e & (O_ - 1);
    w1T[c][k] = W1[e];
  }
  if (t < O_) {
#pragma unroll
    for (int k = CK_; k < 68; ++k) w1T[t][k] = 0.0f;
  }
  for (int e = t; e < O_ * O_; e += 256) {
    int k = e >> 7, c = e & (O_ - 1);
    w2T[c][k] = W2[e];
  }
  float bb1[4], gm[4], bt[4], bb2 = 0.0f;
#pragma unroll
  for (int j = 0; j < 4; ++j) {
    bb1[j] = b1[cg + 32 * j];
    gm[j] = gamma[cg + 32 * j];
    bt[j] = beta[cg + 32 * j];
  }
  if (t < O_) bb2 = b2[t];

  const int bs0 = blockIdx.x * 64;
  const int b = bs0 >> 12;
  const float* fb = features + (size_t)b * N_ * C_;
  const float* xb = xyz + (size_t)b * N_ * 3;

  __syncthreads();

  for (int is = 0; is < 64; ++is) {
    const int bs = bs0 + is;
    const float qx = new_xyz[(size_t)bs * 3 + 0];
    const float qy = new_xyz[(size_t)bs * 3 + 1];
    const float qz = new_xyz[(size_t)bs * 3 + 2];

    for (int e = t; e < K_ * 68; e += 256) {
      int r = e / 68;
      int k = e - r * 68;
      int nbi = knn_idx[(size_t)bs * K_ + r];
      float v;
      if (k < C_) {
        v = fb[(size_t)nbi * C_ + k];
      } else if (k < CK_) {
        float coord = xb[nbi * 3 + (k - C_)];
        float qq = (k == C_) ? qx : ((k == C_ + 1) ? qy : qz);
        v = coord - qq;
      } else {
        v = 0.0f;
      }
      c_l[r][k] = v;
    }
    __syncthreads();

    float h[4][4];
#pragma unroll
    for (int i = 0; i < 4; ++i)
#pragma unroll
      for (int j = 0; j < 4; ++j) h[i][j] = 0.0f;
#pragma unroll
    for (int kc = 0; kc < 17; ++kc) {
      float4 w[4], a[4];
#pragma unroll
      for (int j = 0; j < 4; ++j)
        w[j] = *reinterpret_cast<const float4*>(&w1T[cg + 32 * j][kc * 4]);
#pragma unroll
      for (int i = 0; i < 4; ++i)
        a[i] = *reinterpret_cast<const float4*>(&c_l[4 * g + i][kc * 4]);
#pragma unroll
      for (int i = 0; i < 4; ++i)
#pragma unroll
        for (int j = 0; j < 4; ++j) {
          h[i][j] = fmaf(a[i].x, w[j].x, h[i][j]);
          h[i][j] = fmaf(a[i].y, w[j].y, h[i][j]);
          h[i][j] = fmaf(a[i].z, w[j].z, h[i][j]);
          h[i][j] = fmaf(a[i].w, w[j].w, h[i][j]);
        }
    }
#pragma unroll
    for (int i = 0; i < 4; ++i)
#pragma unroll
      for (int j = 0; j < 4; ++j) h[i][j] += bb1[j];

#pragma unroll
    for (int i = 0; i < 4; ++i) {
      float s1 = (h[i][0] + h[i][1]) + (h[i][2] + h[i][3]);
      float s2 = ((h[i][0] * h[i][0] + h[i][1] * h[i][1]) +
                  (h[i][2] * h[i][2] + h[i][3] * h[i][3]));
#pragma unroll
      for (int off = 1; off <= 16; off <<= 1) {
        s1 += __shfl_xor(s1, off);
        s2 += __shfl_xor(s2, off);
      }
      float mu = s1 * (1.0f / 128.0f);
      float va = fmaf(mu, -mu, s2 * (1.0f / 128.0f));
      float rs = rsqrtf(va + 1e-5f);
#pragma unroll
      for (int j = 0; j < 4; ++j) {
        float hv = fmaf((h[i][j] - mu) * rs, gm[j], bt[j]);
        hp[4 * g + i][cg + 32 * j] = fmaxf(hv, 0.0f);
      }
    }
    __syncthreads();

    float acc[4][4];
#pragma unroll
    for (int i = 0; i < 4; ++i)
#pragma unroll
      for (int j = 0; j < 4; ++j) acc[i][j] = 0.0f;
#pragma unroll 8
    for (int kc = 0; kc < 32; ++kc) {
      float4 w[4], a[4];
#pragma unroll
      for (int j = 0; j < 4; ++j)
        w[j] = *reinterpret_cast<const float4*>(&w2T[cg + 32 * j][kc * 4]);
#pragma unroll
      for (int i = 0; i < 4; ++i)
        a[i] = *reinterpret_cast<const float4*>(&hp[4 * g + i][kc * 4]);
#pragma unroll
      for (int i = 0; i < 4; ++i)
#pragma unroll
        for (int j = 0; j < 4; ++j) {
          acc[i][j] = fmaf(a[i].x, w[j].x, acc[i][j]);
          acc[i][j] = fmaf(a[i].y, w[j].y, acc[i][j]);
          acc[i][j] = fmaf(a[i].z, w[j].z, acc[i][j]);
          acc[i][j] = fmaf(a[i].w, w[j].w, acc[i][j]);
        }
    }
#pragma unroll
    for (int j = 0; j < 4; ++j) {
      float pm = fmaxf(fmaxf(acc[0][j], acc[1][j]), fmaxf(acc[2][j], acc[3][j]));
      pmaxl[g][cg + 32 * j] = pm;
    }
    __syncthreads();

    if (t < O_) {
      float m = pmaxl[0][t];
#pragma unroll
      for (int w = 1; w < 8; ++w) m = fmaxf(m, pmaxl[w][t]);
      out_feat[(size_t)bs * O_ + t] = m + bb2;
    }
    __syncthreads();
  }
}

extern "C" void kernel_launch(void* const* d_in, const int* in_sizes, int n_in,
                              void* d_out, int out_size, void* d_ws, size_t ws_size,
                              hipStream_t stream) {
  const float* xyz      = (const float*)d_in[0];
  const float* features = (const float*)d_in[1];
  const float* W1       = (const float*)d_in[2];
  const float* b1       = (const float*)d_in[3];
  const float* gamma    = (const float*)d_in[4];
  const float* beta     = (const float*)d_in[5];
  const float* W2       = (const float*)d_in[6];
  const float* b2       = (const float*)d_in[7];

  float* out      = (float*)d_out;
  float* new_xyz  = out;                          // [4,4096,3]
  float* new_feat = out + (size_t)B_ * S_ * 3;    // [4,4096,128]
  int* knn_idx = (int*)d_ws;                      // [4,4096,32] = 2 MB
  float4* sorted = (float4*)((char*)d_ws + (size_t)B_ * S_ * K_ * 4);  // 1 MB

  sort_kernel<<<B_, 1024, 0, stream>>>(xyz, sorted);
  fps_kernel<<<B_, 512, 0, stream>>>(xyz, sorted, new_xyz);
  knn_kernel<<<dim3(S_ / 256, B_), 256, 0, stream>>>(new_xyz, knn_idx);
  mlp_kernel<<<B_ * S_ / 64, 256, 0, stream>>>(xyz, features, new_xyz, knn_idx,
                                               W1, b1, gamma, beta, W2, b2,
                                               new_feat);
}